// Round 3
// baseline (302.255 us; speedup 1.0000x reference)
//
#include <hip/hip_runtime.h>

// DepConv3D via bf16 MFMA, register-built B fragments (no LDS, no barriers).
// out[b,oc,h,w] = sum_{t,ic,kd} W[oc,ic,kd,t] * gate(diff,kd) * feat[ic,nbr(t)]
//   diff = depth[nbr]-depth[center]; kd=0 iff diff==-1, kd=1 iff diff==0, else 0.
//   (kd=2 slice unreachable: reference maps diff>=1 to appended zero slice.)
// K = 288, k = t*32 + ic*2 + kd. MFMA 16x16x32_bf16 conventions (m89-verified,
// and validated by the passing round-2 kernel):
//   A: m=lane&15 (oc), kk=(lane>>4)*8+j ; B: n=lane&15 (pixel), kk=(lane>>4)*8+j
//   D: col=lane&15 (pixel), row=(lane>>4)*4+r (oc)

#define IC 16
#define OC 32
#define Hh 512
#define Ww 512
#define HW (Hh * Ww)

typedef __attribute__((ext_vector_type(8))) short short8;   // 8 bf16 = 4 VGPRs
typedef __attribute__((ext_vector_type(4))) float float4v;  // MFMA accum

__device__ __forceinline__ unsigned short f2bf(float x) {
    unsigned u = __float_as_uint(x);
    unsigned r = u + 0x7FFFu + ((u >> 16) & 1u);   // RNE
    return (unsigned short)(r >> 16);
}

// ---- prepass: fp32 weights (32,16,3,3,3) -> bf16 A-fragments in ws ----
// wsA[e], e = c*1024 + mt*512 + lane*8 + j :
//   oc = mt*16 + (lane&15); kk = (lane>>4)*8+j; ic = kk>>1; kd = kk&1; tap = c.
__global__ void prep_weights(const float* __restrict__ wgt,
                             unsigned short* __restrict__ wsA) {
    int e = blockIdx.x * 256 + threadIdx.x;
    if (e >= 9 * 2 * 64 * 8) return;
    int j    = e & 7;
    int lane = (e >> 3) & 63;
    int mt   = (e >> 9) & 1;
    int c    = e >> 10;
    int oc = mt * 16 + (lane & 15);
    int kk = ((lane >> 4) << 3) + j;
    wsA[e] = f2bf(wgt[oc * 432 + (kk >> 1) * 27 + (kk & 1) * 9 + c]);
}

__global__ __launch_bounds__(256) void depconv_mfma_reg(
    const float* __restrict__ feat,   // (4,16,512,512)
    const int*   __restrict__ depth,  // (4,512,512)
    const unsigned short* __restrict__ wsA,
    float*       __restrict__ out)    // (4,32,512,512)
{
    const int tid  = threadIdx.x;
    const int lane = tid & 63;
    const int wv   = tid >> 6;
    const int g    = lane >> 4;   // ic-group: ics 4g..4g+3
    const int n    = lane & 15;   // pixel within 16-wide unit

    // A fragments (L2-resident ws, 18 x 16B coalesced loads)
    short8 afrag[9][2];
    {
        const short8* ap = (const short8*)wsA;
#pragma unroll
        for (int c = 0; c < 9; ++c) {
            afrag[c][0] = ap[(c * 2 + 0) * 64 + lane];
            afrag[c][1] = ap[(c * 2 + 1) * 64 + lane];
        }
    }

    const int P0     = blockIdx.x * 256;          // 256 pixels, same row
    const int b      = P0 >> 18;
    const int hw0    = P0 & (HW - 1);
    const int h      = hw0 >> 9;
    const int wbase  = (hw0 & (Ww - 1)) + wv * 64;  // wave's 64-pixel span

    const int* __restrict__ drow = depth + (b << 18) + h * Ww;

    for (int it = 0; it < 4; ++it) {
        const int w  = wbase + it * 16 + n;       // this lane's pixel
        const int dc = drow[w];

        // bases at (h-1, w-1); taps use immediate offsets kh*Ww + kw
        const float* __restrict__ fb = feat + (size_t)(b * IC + g * 4) * HW + (h - 1) * Ww + (w - 1);
        const int*   __restrict__ db = depth + (b << 18) + (h - 1) * Ww + (w - 1);

        float4v acc0 = {0.f, 0.f, 0.f, 0.f};
        float4v acc1 = {0.f, 0.f, 0.f, 0.f};

#pragma unroll
        for (int t = 0; t < 9; ++t) {
            const int kh = t / 3, kw = t % 3;
            const int y = h + kh - 1;
            const int x = w + kw - 1;
            const bool inb = ((unsigned)y < (unsigned)Hh) & ((unsigned)x < (unsigned)Ww);

            unsigned pk0 = 0, pk1 = 0, pk2 = 0, pk3 = 0;
            if (inb) {
                const int dn   = db[kh * Ww + kw];
                const int diff = dn - dc;
                const bool m0 = (diff == -1);    // kd=0 gate (low 16)
                const bool m1 = (diff == 0);     // kd=1 gate (high 16)
                const unsigned short u0 = f2bf(fb[0 * HW + kh * Ww + kw]);
                const unsigned short u1 = f2bf(fb[1 * HW + kh * Ww + kw]);
                const unsigned short u2 = f2bf(fb[2 * HW + kh * Ww + kw]);
                const unsigned short u3 = f2bf(fb[3 * HW + kh * Ww + kw]);
                pk0 = (m0 ? (unsigned)u0 : 0u) | ((m1 ? (unsigned)u0 : 0u) << 16);
                pk1 = (m0 ? (unsigned)u1 : 0u) | ((m1 ? (unsigned)u1 : 0u) << 16);
                pk2 = (m0 ? (unsigned)u2 : 0u) | ((m1 ? (unsigned)u2 : 0u) << 16);
                pk3 = (m0 ? (unsigned)u3 : 0u) | ((m1 ? (unsigned)u3 : 0u) << 16);
            }
            union { short8 s; unsigned u[4]; } bf;
            bf.u[0] = pk0; bf.u[1] = pk1; bf.u[2] = pk2; bf.u[3] = pk3;

            acc0 = __builtin_amdgcn_mfma_f32_16x16x32_bf16(afrag[t][0], bf.s, acc0, 0, 0, 0);
            acc1 = __builtin_amdgcn_mfma_f32_16x16x32_bf16(afrag[t][1], bf.s, acc1, 0, 0, 0);
        }

        // D: this lane holds pixel col=n (== its build pixel w) rows g*4..g*4+3
        const int rbase = g * 4;
        float* op = out + ((size_t)(b * OC) << 18) + h * Ww + w;
#pragma unroll
        for (int r = 0; r < 4; ++r) {
            op[(size_t)(rbase + r) * HW]      = acc0[r];
            op[(size_t)(16 + rbase + r) * HW] = acc1[r];
        }
    }
}

extern "C" void kernel_launch(void* const* d_in, const int* in_sizes, int n_in,
                              void* d_out, int out_size, void* d_ws, size_t ws_size,
                              hipStream_t stream) {
    const float* feat  = (const float*)d_in[0];
    const int*   depth = (const int*)d_in[1];
    const float* wgt   = (const float*)d_in[2];
    float* out = (float*)d_out;
    unsigned short* wsA = (unsigned short*)d_ws;   // 18,432 B used

    prep_weights<<<36, 256, 0, stream>>>(wgt, wsA);

    const int total = 4 * HW;
    depconv_mfma_reg<<<total / 256, 256, 0, stream>>>(feat, depth, wsA, out);
}

// Round 4
// 245.973 us; speedup vs baseline: 1.2288x; 1.2288x over previous
//
#include <hip/hip_runtime.h>

// DepConv3D via bf16 MFMA with pixel-major bf16 feature transpose prepass.
//   diff = depth[nbr]-depth[center]; kd=0 iff diff==-1, kd=1 iff diff==0, else 0.
//   (kd=2 slice unreachable: reference maps diff>=1 to appended zero slice.)
// K = 288, k = t*32 + ic*2 + kd. MFMA 16x16x32_bf16 conventions (validated by
// passing R2/R3 kernels):
//   A: m=lane&15 (oc), kk=(lane>>4)*8+j ; B: n=lane&15 (pixel), kk=(lane>>4)*8+j
//   D: col=lane&15 (pixel), row=(lane>>4)*4+r (oc)
// B-build: lane (g,n) loads 4 consecutive ics (8 B) from transposed ft, then
// per ic: v_perm half-dup + AND gate-mask (2 VALU/word).

#define IC 16
#define OC 32
#define Hh 512
#define Ww 512
#define HW (Hh * Ww)

typedef __attribute__((ext_vector_type(8))) short short8;
typedef __attribute__((ext_vector_type(4))) float float4v;
typedef __attribute__((ext_vector_type(2))) unsigned int uint2v;
typedef __attribute__((ext_vector_type(4))) unsigned int uint4v;

__device__ __forceinline__ unsigned short f2bf(float x) {
    unsigned u = __float_as_uint(x);
    unsigned r = u + 0x7FFFu + ((u >> 16) & 1u);   // RNE
    return (unsigned short)(r >> 16);
}

// ---- prepass 1: fp32 weights (32,16,3,3,3) -> bf16 A-fragments ----
__global__ void prep_weights(const float* __restrict__ wgt,
                             unsigned short* __restrict__ wsA) {
    int e = blockIdx.x * 256 + threadIdx.x;
    if (e >= 9 * 2 * 64 * 8) return;
    int j    = e & 7;
    int lane = (e >> 3) & 63;
    int mt   = (e >> 9) & 1;
    int c    = e >> 10;
    int oc = mt * 16 + (lane & 15);
    int kk = ((lane >> 4) << 3) + j;
    wsA[e] = f2bf(wgt[oc * 432 + (kk >> 1) * 27 + (kk & 1) * 9 + c]);
}

// ---- prepass 2: fp32 planar (b,ic,h,w) -> bf16 pixel-major ft[p*16+ic] ----
__global__ __launch_bounds__(256) void prep_feat(const float* __restrict__ feat,
                                                 unsigned short* __restrict__ ft) {
    int p = blockIdx.x * 256 + threadIdx.x;      // pixel over 4*HW
    int b = p >> 18, hw = p & (HW - 1);
    const float* fp = feat + (size_t)b * IC * HW + hw;
    unsigned pk[8];
#pragma unroll
    for (int i = 0; i < 8; ++i) {
        float a = fp[(size_t)(2 * i) * HW];
        float c = fp[(size_t)(2 * i + 1) * HW];
        pk[i] = (unsigned)f2bf(a) | ((unsigned)f2bf(c) << 16);
    }
    uint4v* dst = (uint4v*)(ft + (size_t)p * 16);
    dst[0] = (uint4v){pk[0], pk[1], pk[2], pk[3]};
    dst[1] = (uint4v){pk[4], pk[5], pk[6], pk[7]};
}

// ---- main kernel: transposed-bf16 B-build, no LDS, no barriers ----
__global__ __launch_bounds__(256) void depconv_mfma_t(
    const unsigned short* __restrict__ ft,    // (4,512,512,16) bf16
    const int*   __restrict__ depth,          // (4,512,512)
    const unsigned short* __restrict__ wsA,
    float*       __restrict__ out)            // (4,32,512,512)
{
    const int tid  = threadIdx.x;
    const int lane = tid & 63;
    const int wv   = tid >> 6;
    const int g    = lane >> 4;   // ic-group: ics 4g..4g+3
    const int n    = lane & 15;

    short8 afrag[9][2];
    {
        const short8* ap = (const short8*)wsA;
#pragma unroll
        for (int c = 0; c < 9; ++c) {
            afrag[c][0] = ap[(c * 2 + 0) * 64 + lane];
            afrag[c][1] = ap[(c * 2 + 1) * 64 + lane];
        }
    }

    const int P0    = blockIdx.x * 256;       // 256 pixels, single row
    const int b     = P0 >> 18;
    const int hw0   = P0 & (HW - 1);
    const int h     = hw0 >> 9;
    const int wbase = (hw0 & (Ww - 1)) + wv * 64;

    const int y0 = (h == 0) ? 0 : h - 1;
    const int y2 = (h == Hh - 1) ? Hh - 1 : h + 1;
    const unsigned short* frow[3];
    const int* drow[3];
    frow[0] = ft + ((size_t)((b << 18) + y0 * Ww) << 4);
    frow[1] = ft + ((size_t)((b << 18) + h  * Ww) << 4);
    frow[2] = ft + ((size_t)((b << 18) + y2 * Ww) << 4);
    drow[0] = depth + (b << 18) + y0 * Ww;
    drow[1] = depth + (b << 18) + h  * Ww;
    drow[2] = depth + (b << 18) + y2 * Ww;

    for (int it = 0; it < 4; ++it) {
        const int w  = wbase + it * 16 + n;
        const int dc = drow[1][w];
        const int x0 = (w == 0) ? 0 : w - 1;
        const int x2 = (w == Ww - 1) ? Ww - 1 : w + 1;
        const int xs[3] = {x0, w, x2};

        float4v acc0 = {0.f, 0.f, 0.f, 0.f};
        float4v acc1 = {0.f, 0.f, 0.f, 0.f};

#pragma unroll
        for (int t = 0; t < 9; ++t) {
            const int kh = t / 3, kw = t % 3;
            unsigned mm;
            if (t == 4) {
                mm = 0xffff0000u;   // center: diff==0 always, kd=1 slice
            } else {
                const bool inb = !((kh == 0 && h == 0) || (kh == 2 && h == Hh - 1) ||
                                   (kw == 0 && w == 0) || (kw == 2 && w == Ww - 1));
                const int dn   = drow[kh][xs[kw]];
                const int diff = dn - dc;
                mm = (diff == 0) ? 0xffff0000u : ((diff == -1) ? 0x0000ffffu : 0u);
                if (!inb) mm = 0u;
            }
            // 4 ics of this lane's neighbor pixel: one 8 B load
            const uint2v pr = *(const uint2v*)(frow[kh] + (((size_t)xs[kw]) << 4) + g * 4);
            union { short8 s; unsigned u[4]; } bf;
            bf.u[0] = __builtin_amdgcn_perm(0u, pr.x, 0x01000100u) & mm;  // ic 4g+0
            bf.u[1] = __builtin_amdgcn_perm(0u, pr.x, 0x03020302u) & mm;  // ic 4g+1
            bf.u[2] = __builtin_amdgcn_perm(0u, pr.y, 0x01000100u) & mm;  // ic 4g+2
            bf.u[3] = __builtin_amdgcn_perm(0u, pr.y, 0x03020302u) & mm;  // ic 4g+3

            acc0 = __builtin_amdgcn_mfma_f32_16x16x32_bf16(afrag[t][0], bf.s, acc0, 0, 0, 0);
            acc1 = __builtin_amdgcn_mfma_f32_16x16x32_bf16(afrag[t][1], bf.s, acc1, 0, 0, 0);
        }

        const int rbase = g * 4;
        float* op = out + ((size_t)(b * OC) << 18) + h * Ww + w;
#pragma unroll
        for (int r = 0; r < 4; ++r) {
            op[(size_t)(rbase + r) * HW]      = acc0[r];
            op[(size_t)(16 + rbase + r) * HW] = acc1[r];
        }
    }
}

// ---- fallback main kernel (R3): used only if ws can't hold the transpose ----
__global__ __launch_bounds__(256) void depconv_mfma_reg(
    const float* __restrict__ feat,
    const int*   __restrict__ depth,
    const unsigned short* __restrict__ wsA,
    float*       __restrict__ out)
{
    const int tid  = threadIdx.x;
    const int lane = tid & 63;
    const int wv   = tid >> 6;
    const int g    = lane >> 4;
    const int n    = lane & 15;

    short8 afrag[9][2];
    {
        const short8* ap = (const short8*)wsA;
#pragma unroll
        for (int c = 0; c < 9; ++c) {
            afrag[c][0] = ap[(c * 2 + 0) * 64 + lane];
            afrag[c][1] = ap[(c * 2 + 1) * 64 + lane];
        }
    }

    const int P0    = blockIdx.x * 256;
    const int b     = P0 >> 18;
    const int hw0   = P0 & (HW - 1);
    const int h     = hw0 >> 9;
    const int wbase = (hw0 & (Ww - 1)) + wv * 64;
    const int* __restrict__ drow = depth + (b << 18) + h * Ww;

    for (int it = 0; it < 4; ++it) {
        const int w  = wbase + it * 16 + n;
        const int dc = drow[w];
        const float* __restrict__ fb = feat + (size_t)(b * IC + g * 4) * HW + (h - 1) * Ww + (w - 1);
        const int*   __restrict__ db = depth + (b << 18) + (h - 1) * Ww + (w - 1);

        float4v acc0 = {0.f, 0.f, 0.f, 0.f};
        float4v acc1 = {0.f, 0.f, 0.f, 0.f};
#pragma unroll
        for (int t = 0; t < 9; ++t) {
            const int kh = t / 3, kw = t % 3;
            const int y = h + kh - 1;
            const int x = w + kw - 1;
            const bool inb = ((unsigned)y < (unsigned)Hh) & ((unsigned)x < (unsigned)Ww);
            unsigned pk0 = 0, pk1 = 0, pk2 = 0, pk3 = 0;
            if (inb) {
                const int dn   = db[kh * Ww + kw];
                const int diff = dn - dc;
                const bool m0 = (diff == -1);
                const bool m1 = (diff == 0);
                const unsigned short u0 = f2bf(fb[0 * HW + kh * Ww + kw]);
                const unsigned short u1 = f2bf(fb[1 * HW + kh * Ww + kw]);
                const unsigned short u2 = f2bf(fb[2 * HW + kh * Ww + kw]);
                const unsigned short u3 = f2bf(fb[3 * HW + kh * Ww + kw]);
                pk0 = (m0 ? (unsigned)u0 : 0u) | ((m1 ? (unsigned)u0 : 0u) << 16);
                pk1 = (m0 ? (unsigned)u1 : 0u) | ((m1 ? (unsigned)u1 : 0u) << 16);
                pk2 = (m0 ? (unsigned)u2 : 0u) | ((m1 ? (unsigned)u2 : 0u) << 16);
                pk3 = (m0 ? (unsigned)u3 : 0u) | ((m1 ? (unsigned)u3 : 0u) << 16);
            }
            union { short8 s; unsigned u[4]; } bfv;
            bfv.u[0] = pk0; bfv.u[1] = pk1; bfv.u[2] = pk2; bfv.u[3] = pk3;
            acc0 = __builtin_amdgcn_mfma_f32_16x16x32_bf16(afrag[t][0], bfv.s, acc0, 0, 0, 0);
            acc1 = __builtin_amdgcn_mfma_f32_16x16x32_bf16(afrag[t][1], bfv.s, acc1, 0, 0, 0);
        }

        const int rbase = g * 4;
        float* op = out + ((size_t)(b * OC) << 18) + h * Ww + w;
#pragma unroll
        for (int r = 0; r < 4; ++r) {
            op[(size_t)(rbase + r) * HW]      = acc0[r];
            op[(size_t)(16 + rbase + r) * HW] = acc1[r];
        }
    }
}

extern "C" void kernel_launch(void* const* d_in, const int* in_sizes, int n_in,
                              void* d_out, int out_size, void* d_ws, size_t ws_size,
                              hipStream_t stream) {
    const float* feat  = (const float*)d_in[0];
    const int*   depth = (const int*)d_in[1];
    const float* wgt   = (const float*)d_in[2];
    float* out = (float*)d_out;

    unsigned short* wsA = (unsigned short*)d_ws;                       // 18,432 B
    unsigned short* ft  = (unsigned short*)((char*)d_ws + 32768);      // 33,554,432 B

    prep_weights<<<36, 256, 0, stream>>>(wgt, wsA);

    const int total = 4 * HW;   // 1,048,576 pixels
    if (ws_size >= (size_t)32768 + (size_t)total * IC * 2) {
        prep_feat<<<total / 256, 256, 0, stream>>>(feat, ft);
        depconv_mfma_t<<<total / 256, 256, 0, stream>>>(ft, depth, wsA, out);
    } else {
        depconv_mfma_reg<<<total / 256, 256, 0, stream>>>(feat, depth, wsA, out);
    }
}